// Round 3
// baseline (911.301 us; speedup 1.0000x reference)
//
#include <hip/hip_runtime.h>
#include <cstddef>

#define EPS_ 1e-5f

// Problem constants: B=32, C=256, L=4096, I=64
// x layout [B][C][L] row-major; elem (b,c,l) at (b*256+c)*4096 + l.

// ---- ws float offsets ----
// Folded weights: W1t[c][i] = s1[i]*w1[br][i][c]; W2t[i][c] = s2[c]*w2[br][c][i]
#define OFF_W1T0 0
#define OFF_W2T0 16384
#define OFF_W1T2 32768
#define OFF_W2T2 49152
#define OFF_C1_0 65536   // 64   c1 = bn1_b + s1*(b1 - bn1_m)
#define OFF_C2_0 65600   // 256
#define OFF_C1_2 65856   // 64
#define OFF_C2_2 65920   // 256
#define OFF_MEANAB 66176 // [32][256]
#define OFF_SUMABC 74368 // [32][256] (atomic accum, zeroed in prep)
#define OFF_G1 82560     // [32][256]
#define OFF_G3 90752     // [32][256]
#define OFF_XO1 131072   // [32][256][4096]
#define OFF_P 33685504   // [32][256][4096]  p = 0.5*(1-wei)*x_c
// total ws need: 67239936 floats = ~269 MB

// ============ prep: fold BN into weights, zero sum_abc ============
__global__ __launch_bounds__(256) void k_prep(
    const float* __restrict__ w1, const float* __restrict__ b1,
    const float* __restrict__ bn1g, const float* __restrict__ bn1b,
    const float* __restrict__ bn1m, const float* __restrict__ bn1v,
    const float* __restrict__ w2, const float* __restrict__ b2,
    const float* __restrict__ bn2g, const float* __restrict__ bn2b,
    const float* __restrict__ bn2m, const float* __restrict__ bn2v,
    float* __restrict__ ws)
{
  int idx = blockIdx.x * 256 + threadIdx.x;
  if (idx < 32768) {                       // W1t, branches 0 and 2
    int slot = idx >> 14, r = idx & 16383;
    int br = slot << 1;
    int c = r >> 6, i = r & 63;
    int gi = (br << 6) + i;
    float s1 = bn1g[gi] / sqrtf(bn1v[gi] + EPS_);
    ws[OFF_W1T0 + (slot << 15) + r] = w1[gi * 256 + c] * s1;
  } else if (idx < 65536) {                // W2t
    int j = idx - 32768;
    int slot = j >> 14, r = j & 16383;
    int br = slot << 1;
    int i = r >> 8, c = r & 255;
    int gc = (br << 8) + c;
    float s2 = bn2g[gc] / sqrtf(bn2v[gc] + EPS_);
    ws[OFF_W2T0 + (slot << 15) + r] = w2[gc * 64 + i] * s2;
  } else if (idx < 65664) {                // c1
    int j = idx - 65536;
    int slot = j >> 6, i = j & 63;
    int gi = ((slot << 1) << 6) + i;
    float s1 = bn1g[gi] / sqrtf(bn1v[gi] + EPS_);
    ws[OFF_C1_0 + slot * 320 + i] = bn1b[gi] + s1 * (b1[gi] - bn1m[gi]);
  } else if (idx < 66176) {                // c2
    int j = idx - 65664;
    int slot = j >> 8, c = j & 255;
    int gc = ((slot << 1) << 8) + c;
    float s2 = bn2g[gc] / sqrtf(bn2v[gc] + EPS_);
    ws[OFF_C2_0 + slot * 320 + c] = bn2b[gc] + s2 * (b2[gc] - bn2m[gc]);
  } else if (idx < 74368) {                // zero sum_abc
    ws[OFF_SUMABC + (idx - 66176)] = 0.0f;
  }
}

// ============ K1: mean over L of (x_a + x_b), one block per (b,c) ============
__global__ __launch_bounds__(256) void k_mean_ab(
    const float* __restrict__ xa, const float* __restrict__ xb,
    float* __restrict__ mean_ab)
{
  const int row = blockIdx.x;              // b*256 + c
  const size_t base4 = (size_t)row * 1024; // float4 units
  const float4* a4 = (const float4*)xa;
  const float4* b4 = (const float4*)xb;
  float s = 0.0f;
#pragma unroll
  for (int k = 0; k < 4; ++k) {
    float4 va = a4[base4 + k * 256 + threadIdx.x];
    float4 vb = b4[base4 + k * 256 + threadIdx.x];
    s += (va.x + vb.x) + (va.y + vb.y) + (va.z + vb.z) + (va.w + vb.w);
  }
#pragma unroll
  for (int m = 32; m; m >>= 1) s += __shfl_xor(s, m, 64);
  __shared__ float part[4];
  if ((threadIdx.x & 63) == 0) part[threadIdx.x >> 6] = s;
  __syncthreads();
  if (threadIdx.x == 0)
    mean_ab[row] = (part[0] + part[1] + part[2] + part[3]) * (1.0f / 4096.0f);
}

// ============ global-pool attention branch (br = 1 or 3), one block per b ===
__global__ __launch_bounds__(256) void k_gatt(
    int br, const float* __restrict__ vin, float scale,
    const float* __restrict__ w1, const float* __restrict__ b1,
    const float* __restrict__ bn1g, const float* __restrict__ bn1b,
    const float* __restrict__ bn1m, const float* __restrict__ bn1v,
    const float* __restrict__ w2, const float* __restrict__ b2,
    const float* __restrict__ bn2g, const float* __restrict__ bn2b,
    const float* __restrict__ bn2m, const float* __restrict__ bn2v,
    float* __restrict__ gout)
{
  const int b = blockIdx.x, tid = threadIdx.x;
  __shared__ float xs[256];
  __shared__ float as[64];
  xs[tid] = vin[(b << 8) + tid] * scale;
  __syncthreads();
  if (tid < 64) {
    const int gi = (br << 6) + tid;
    const float* wr = w1 + gi * 256;
    float acc = 0.0f;
#pragma unroll 8
    for (int c = 0; c < 256; ++c) acc = fmaf(wr[c], xs[c], acc);
    float s1 = bn1g[gi] / sqrtf(bn1v[gi] + EPS_);
    float h = s1 * (acc + b1[gi] - bn1m[gi]) + bn1b[gi];
    as[tid] = fmaxf(h, 0.0f);
  }
  __syncthreads();
  const int gc = (br << 8) + tid;
  const float* wr2 = w2 + gc * 64;
  float acc = 0.0f;
#pragma unroll 8
  for (int i = 0; i < 64; ++i) acc = fmaf(wr2[i], as[i], acc);
  float s2 = bn2g[gc] / sqrtf(bn2v[gc] + EPS_);
  gout[(b << 8) + tid] = s2 * (acc + b2[gc] - bn2m[gc]) + bn2b[gc];
}

// ============ K2: local attn branch 0 + first blend ============
// 2048 blocks x 512 threads (8 waves); block = (b, 64-position l-tile).
// lane = position l; wave = output-row slice (8 i-rows / 32 channels).
// W accesses are wave-uniform -> SGPR s_load; inner loop v_fmac(s,v).
// K=256 staged in 4 double-buffered chunks of 64c x 64l (2x16 KB).
__global__ __launch_bounds__(512, 6) void k_local1(
    const float* __restrict__ xa, const float* __restrict__ xb,
    const float* __restrict__ xc,
    const float* __restrict__ W1t, const float* __restrict__ W2t,
    const float* __restrict__ c1, const float* __restrict__ c2,
    const float* __restrict__ g1,
    float* __restrict__ xo1, float* __restrict__ pbuf,
    float* __restrict__ sumabc)
{
  const int tid = threadIdx.x;
  const int lane = tid & 63;
  const int wav = __builtin_amdgcn_readfirstlane(tid >> 6);
  const int b = blockIdx.x >> 6;
  const int l0 = (blockIdx.x & 63) << 6;
  __shared__ float xs[2][64][64];          // chunk double-buffer (32 KB)
  __shared__ float hs[64][64];             // h tile (16 KB)
  __shared__ float cgs[256];               // c2 + g1 row
  const size_t rowbase = ((size_t)b << 20) + (size_t)l0;

  if (tid < 256) cgs[tid] = c2[tid] + g1[(b << 8) + tid];

  // staging map: thread -> rows (tid>>4) and (tid>>4)+32, cols (tid&15)*4
  const int srow = tid >> 4;
  const int scol = (tid & 15) << 2;

  float4 ra0, rb0, ra1, rb1;
  { // prologue: load chunk 0
    const size_t o0 = rowbase + ((size_t)srow << 12) + scol;
    const size_t o1 = rowbase + ((size_t)(srow + 32) << 12) + scol;
    ra0 = *(const float4*)(xa + o0); rb0 = *(const float4*)(xb + o0);
    ra1 = *(const float4*)(xa + o1); rb1 = *(const float4*)(xb + o1);
  }
  {
    float4 v0 = {ra0.x + rb0.x, ra0.y + rb0.y, ra0.z + rb0.z, ra0.w + rb0.w};
    float4 v1 = {ra1.x + rb1.x, ra1.y + rb1.y, ra1.z + rb1.z, ra1.w + rb1.w};
    *(float4*)&xs[0][srow][scol] = v0;
    *(float4*)&xs[0][srow + 32][scol] = v1;
  }
  __syncthreads();

  // ---- layer 1: acc[8] per lane (wave's 8 i-rows x lane's position) ----
  const int i0 = wav << 3;
  float acc[8] = {0.f, 0.f, 0.f, 0.f, 0.f, 0.f, 0.f, 0.f};
  const float* __restrict__ w1base = W1t + i0;
  for (int kb = 0; kb < 4; ++kb) {
    if (kb < 3) { // issue next chunk's loads early (hidden under compute)
      const size_t cb = rowbase + ((size_t)((kb + 1) << 6) << 12);
      const size_t o0 = cb + ((size_t)srow << 12) + scol;
      const size_t o1 = cb + ((size_t)(srow + 32) << 12) + scol;
      ra0 = *(const float4*)(xa + o0); rb0 = *(const float4*)(xb + o0);
      ra1 = *(const float4*)(xa + o1); rb1 = *(const float4*)(xb + o1);
    }
    const float* __restrict__ wr0 = w1base + ((kb << 6) << 6);
    const int pb = kb & 1;
#pragma unroll 2
    for (int c = 0; c < 64; ++c) {
      const float xv = xs[pb][c][lane];
      const float* wr = wr0 + (c << 6);
#pragma unroll
      for (int i = 0; i < 8; ++i) acc[i] = fmaf(wr[i], xv, acc[i]);
    }
    __syncthreads();
    if (kb < 3) { // write next chunk into the other buffer
      const int nb = (kb + 1) & 1;
      float4 v0 = {ra0.x + rb0.x, ra0.y + rb0.y, ra0.z + rb0.z, ra0.w + rb0.w};
      float4 v1 = {ra1.x + rb1.x, ra1.y + rb1.y, ra1.z + rb1.z, ra1.w + rb1.w};
      *(float4*)&xs[nb][srow][scol] = v0;
      *(float4*)&xs[nb][srow + 32][scol] = v1;
      __syncthreads();
    }
  }

  // ---- bias + ReLU -> hs ----
#pragma unroll
  for (int i = 0; i < 8; ++i)
    hs[i0 + i][lane] = fmaxf(acc[i] + c1[i0 + i], 0.0f);
  __syncthreads();

  // ---- layer 2: acc2[32] per lane (wave's 32 channels x lane's position) ----
  const int cc0 = wav << 5;
  float acc2[32];
#pragma unroll
  for (int j = 0; j < 32; ++j) acc2[j] = 0.0f;
  const float* __restrict__ w2base = W2t + cc0;
  for (int ii = 0; ii < 64; ++ii) {
    const float hv = hs[ii][lane];
    const float* wr = w2base + (ii << 8);
#pragma unroll
    for (int j = 0; j < 32; ++j) acc2[j] = fmaf(wr[j], hv, acc2[j]);
  }

  // ---- sigmoid + blend + partial sums ----
  for (int j = 0; j < 32; ++j) {
    const int cc = cc0 + j;
    const size_t off = rowbase + ((size_t)cc << 12) + (size_t)lane;
    const float w = 1.0f / (1.0f + __expf(-(acc2[j] + cgs[cc])));
    const float a = xa[off], bb = xb[off], q = xc[off];
    const float xo = fmaf(a - bb, w, bb);       // a*w + b*(1-w)
    xo1[off] = xo;
    pbuf[off] = 0.5f * (1.0f - w) * q;
    float s = xo + q;
#pragma unroll
    for (int m = 1; m < 64; m <<= 1) s += __shfl_xor(s, m, 64);
    if (lane == 0) atomicAdd(&sumabc[(b << 8) + cc], s);
  }
}

// ============ K4: local attn branch 2 + final combine ============
// out = 0.5*xo1*(1+wei2) + p
__global__ __launch_bounds__(512, 6) void k_local2(
    const float* __restrict__ xo1, const float* __restrict__ xc,
    const float* __restrict__ pbuf,
    const float* __restrict__ W1t, const float* __restrict__ W2t,
    const float* __restrict__ c1, const float* __restrict__ c2,
    const float* __restrict__ g3,
    float* __restrict__ outp)
{
  const int tid = threadIdx.x;
  const int lane = tid & 63;
  const int wav = __builtin_amdgcn_readfirstlane(tid >> 6);
  const int b = blockIdx.x >> 6;
  const int l0 = (blockIdx.x & 63) << 6;
  __shared__ float xs[2][64][64];
  __shared__ float hs[64][64];
  __shared__ float cgs[256];
  const size_t rowbase = ((size_t)b << 20) + (size_t)l0;

  if (tid < 256) cgs[tid] = c2[tid] + g3[(b << 8) + tid];

  const int srow = tid >> 4;
  const int scol = (tid & 15) << 2;

  float4 ra0, rb0, ra1, rb1;
  {
    const size_t o0 = rowbase + ((size_t)srow << 12) + scol;
    const size_t o1 = rowbase + ((size_t)(srow + 32) << 12) + scol;
    ra0 = *(const float4*)(xo1 + o0); rb0 = *(const float4*)(xc + o0);
    ra1 = *(const float4*)(xo1 + o1); rb1 = *(const float4*)(xc + o1);
  }
  {
    float4 v0 = {ra0.x + rb0.x, ra0.y + rb0.y, ra0.z + rb0.z, ra0.w + rb0.w};
    float4 v1 = {ra1.x + rb1.x, ra1.y + rb1.y, ra1.z + rb1.z, ra1.w + rb1.w};
    *(float4*)&xs[0][srow][scol] = v0;
    *(float4*)&xs[0][srow + 32][scol] = v1;
  }
  __syncthreads();

  const int i0 = wav << 3;
  float acc[8] = {0.f, 0.f, 0.f, 0.f, 0.f, 0.f, 0.f, 0.f};
  const float* __restrict__ w1base = W1t + i0;
  for (int kb = 0; kb < 4; ++kb) {
    if (kb < 3) {
      const size_t cb = rowbase + ((size_t)((kb + 1) << 6) << 12);
      const size_t o0 = cb + ((size_t)srow << 12) + scol;
      const size_t o1 = cb + ((size_t)(srow + 32) << 12) + scol;
      ra0 = *(const float4*)(xo1 + o0); rb0 = *(const float4*)(xc + o0);
      ra1 = *(const float4*)(xo1 + o1); rb1 = *(const float4*)(xc + o1);
    }
    const float* __restrict__ wr0 = w1base + ((kb << 6) << 6);
    const int pb = kb & 1;
#pragma unroll 2
    for (int c = 0; c < 64; ++c) {
      const float xv = xs[pb][c][lane];
      const float* wr = wr0 + (c << 6);
#pragma unroll
      for (int i = 0; i < 8; ++i) acc[i] = fmaf(wr[i], xv, acc[i]);
    }
    __syncthreads();
    if (kb < 3) {
      const int nb = (kb + 1) & 1;
      float4 v0 = {ra0.x + rb0.x, ra0.y + rb0.y, ra0.z + rb0.z, ra0.w + rb0.w};
      float4 v1 = {ra1.x + rb1.x, ra1.y + rb1.y, ra1.z + rb1.z, ra1.w + rb1.w};
      *(float4*)&xs[nb][srow][scol] = v0;
      *(float4*)&xs[nb][srow + 32][scol] = v1;
      __syncthreads();
    }
  }

#pragma unroll
  for (int i = 0; i < 8; ++i)
    hs[i0 + i][lane] = fmaxf(acc[i] + c1[i0 + i], 0.0f);
  __syncthreads();

  const int cc0 = wav << 5;
  float acc2[32];
#pragma unroll
  for (int j = 0; j < 32; ++j) acc2[j] = 0.0f;
  const float* __restrict__ w2base = W2t + cc0;
  for (int ii = 0; ii < 64; ++ii) {
    const float hv = hs[ii][lane];
    const float* wr = w2base + (ii << 8);
#pragma unroll
    for (int j = 0; j < 32; ++j) acc2[j] = fmaf(wr[j], hv, acc2[j]);
  }

  for (int j = 0; j < 32; ++j) {
    const int cc = cc0 + j;
    const size_t off = rowbase + ((size_t)cc << 12) + (size_t)lane;
    const float w2s = 1.0f / (1.0f + __expf(-(acc2[j] + cgs[cc])));
    const float xov = xo1[off];
    const float pv = pbuf[off];
    outp[off] = fmaf(0.5f * xov, w2s, fmaf(0.5f, xov, pv));
  }
}

extern "C" void kernel_launch(void* const* d_in, const int* in_sizes, int n_in,
                              void* d_out, int out_size, void* d_ws, size_t ws_size,
                              hipStream_t stream) {
  const float* xa = (const float*)d_in[0];
  const float* xb = (const float*)d_in[1];
  const float* xc = (const float*)d_in[2];
  const float* w1 = (const float*)d_in[3];
  const float* b1 = (const float*)d_in[4];
  const float* bn1g = (const float*)d_in[5];
  const float* bn1b = (const float*)d_in[6];
  const float* bn1m = (const float*)d_in[7];
  const float* bn1v = (const float*)d_in[8];
  const float* w2 = (const float*)d_in[9];
  const float* b2 = (const float*)d_in[10];
  const float* bn2g = (const float*)d_in[11];
  const float* bn2b = (const float*)d_in[12];
  const float* bn2m = (const float*)d_in[13];
  const float* bn2v = (const float*)d_in[14];
  float* ws = (float*)d_ws;
  float* outp = (float*)d_out;

  float* W1t0 = ws + OFF_W1T0;
  float* W2t0 = ws + OFF_W2T0;
  float* W1t2 = ws + OFF_W1T2;
  float* W2t2 = ws + OFF_W2T2;
  float* c1_0 = ws + OFF_C1_0;
  float* c2_0 = ws + OFF_C2_0;
  float* c1_2 = ws + OFF_C1_2;
  float* c2_2 = ws + OFF_C2_2;
  float* mean_ab = ws + OFF_MEANAB;
  float* sum_abc = ws + OFF_SUMABC;
  float* g1 = ws + OFF_G1;
  float* g3 = ws + OFF_G3;
  float* xo1 = ws + OFF_XO1;
  float* pbuf = ws + OFF_P;

  // 1) fold BN into weights; zero the round-2 mean accumulator
  k_prep<<<291, 256, 0, stream>>>(w1, b1, bn1g, bn1b, bn1m, bn1v,
                                  w2, b2, bn2g, bn2b, bn2m, bn2v, ws);
  // 2) mean over L of x_a+x_b  (one block per (b,c))
  k_mean_ab<<<8192, 256, 0, stream>>>(xa, xb, mean_ab);
  // 3) global-pool branch 1
  k_gatt<<<32, 256, 0, stream>>>(1, mean_ab, 1.0f,
                                 w1, b1, bn1g, bn1b, bn1m, bn1v,
                                 w2, b2, bn2g, bn2b, bn2m, bn2v, g1);
  // 4) local branch 0 + blend -> xo1, p, sum_abc
  k_local1<<<2048, 512, 0, stream>>>(xa, xb, xc, W1t0, W2t0, c1_0, c2_0, g1,
                                     xo1, pbuf, sum_abc);
  // 5) global-pool branch 3 on mean(xo1 + x_c)
  k_gatt<<<32, 256, 0, stream>>>(3, sum_abc, 1.0f / 4096.0f,
                                 w1, b1, bn1g, bn1b, bn1m, bn1v,
                                 w2, b2, bn2g, bn2b, bn2m, bn2v, g3);
  // 6) local branch 2 + final combine -> out
  k_local2<<<2048, 512, 0, stream>>>(xo1, xc, pbuf, W1t2, W2t2, c1_2, c2_2, g3,
                                     outp);
}

// Round 5
// 749.312 us; speedup vs baseline: 1.2162x; 1.2162x over previous
//
#include <hip/hip_runtime.h>
#include <cstddef>
#include <cstdint>

#define EPS_ 1e-5f

// Problem constants: B=32, C=256, L=4096, I=64
// x layout [B][C][L]; elem (b,c,l) at (b*256+c)*4096 + l.

typedef _Float16 f16x8 __attribute__((ext_vector_type(8)));
typedef float   f32x4 __attribute__((ext_vector_type(4)));

// ---- ws layout ----
// f16 region (from byte 0): W1A0[16384] W1A2[16384] W2A0[16384] W2A2[16384]
//  sigma(g,e) = 4g + (e&3) + 16*(e>>2)   (same assumed k-map on A and B sides;
//  correctness is invariant to the true HW k-map as long as both sides match)
//  W1A frag order: [it(4)][kk(8)][lane(64)][e(8)]:
//    value = s1[i]*w1[br][i = it*16+(lane&15)][c = kk*32 + sigma(lane>>4,e)]
//  W2A frag order: [rt(16)][kk2(2)][lane(64)][e(8)]:
//    value = s2[c]*w2[br][c = rt*16+(lane&15)][ik = kk2*32 + sigma(lane>>4,e)]
// f32 offsets:
#define OFF_C1_0 32768
#define OFF_C1_2 32832
#define OFF_C2_0 32896
#define OFF_C2_2 33152
#define OFF_MEANAB 33408   // [32][256]
#define OFF_MEANC  41600   // [32][256]
#define OFF_SUMXO  49792   // [32][256] zeroed by prep, atomically accumulated
#define OFF_G1 57984       // [32][256]
#define OFF_G3 66176       // [32][256]
#define OFF_XO1 131072     // [32][256][4096] f32
#define OFF_WEI16 33685504 // f32 offset; holds [32][256][4096] f16

#define MFMA16(A, B, C) __builtin_amdgcn_mfma_f32_16x16x32_f16((A), (B), (C), 0, 0, 0)

// ============ prep: fold BN into f16 fragment-ordered weights ============
__global__ __launch_bounds__(256) void k_prep(
    const float* __restrict__ w1, const float* __restrict__ b1,
    const float* __restrict__ bn1g, const float* __restrict__ bn1b,
    const float* __restrict__ bn1m, const float* __restrict__ bn1v,
    const float* __restrict__ w2, const float* __restrict__ b2,
    const float* __restrict__ bn2g, const float* __restrict__ bn2b,
    const float* __restrict__ bn2m, const float* __restrict__ bn2v,
    float* __restrict__ ws)
{
  _Float16* ws16 = (_Float16*)ws;
  int idx = blockIdx.x * 256 + threadIdx.x;
  if (idx < 32768) {                       // W1A, branches 0 and 2
    int slot = idx >> 14, r = idx & 16383;
    int it = r >> 12, kk = (r >> 9) & 7, lane = (r >> 3) & 63, e = r & 7;
    int br = slot << 1;
    int i = it * 16 + (lane & 15);
    int c = kk * 32 + ((lane >> 4) << 2) + (e & 3) + ((e >> 2) << 4);
    int gi = (br << 6) + i;
    float s1 = bn1g[gi] / sqrtf(bn1v[gi] + EPS_);
    ws16[slot * 16384 + r] = (_Float16)(w1[gi * 256 + c] * s1);
  } else if (idx < 65536) {                // W2A
    int d = idx - 32768;
    int slot = d >> 14, r = d & 16383;
    int rt = r >> 10, kk2 = (r >> 9) & 1, lane = (r >> 3) & 63, e = r & 7;
    int br = slot << 1;
    int crow = rt * 16 + (lane & 15);
    int ik = kk2 * 32 + ((lane >> 4) << 2) + (e & 3) + ((e >> 2) << 4);
    int gc = (br << 8) + crow;
    float s2 = bn2g[gc] / sqrtf(bn2v[gc] + EPS_);
    ws16[32768 + slot * 16384 + r] = (_Float16)(w2[gc * 64 + ik] * s2);
  } else if (idx < 65664) {                // c1 (both branches)
    int d = idx - 65536;
    int slot = d >> 6, i = d & 63;
    int gi = slot * 128 + i;
    float s1 = bn1g[gi] / sqrtf(bn1v[gi] + EPS_);
    ws[OFF_C1_0 + slot * 64 + i] = bn1b[gi] + s1 * (b1[gi] - bn1m[gi]);
  } else if (idx < 66176) {                // c2 (both branches)
    int d = idx - 65664;
    int slot = d >> 8, cc = d & 255;
    int gc = slot * 512 + cc;
    float s2 = bn2g[gc] / sqrtf(bn2v[gc] + EPS_);
    ws[OFF_C2_0 + slot * 256 + cc] = bn2b[gc] + s2 * (b2[gc] - bn2m[gc]);
  } else if (idx < 74368) {                // zero sumxo
    ws[OFF_SUMXO + (idx - 66176)] = 0.0f;
  }
}

// ============ K1: means over L of (x_a+x_b) and x_c ============
__global__ __launch_bounds__(256) void k_mean3(
    const float* __restrict__ xa, const float* __restrict__ xb,
    const float* __restrict__ xc,
    float* __restrict__ mean_ab, float* __restrict__ mean_c)
{
  const int row = blockIdx.x;              // b*256 + c
  const size_t base4 = (size_t)row * 1024; // float4 units
  const float4* a4 = (const float4*)xa;
  const float4* b4 = (const float4*)xb;
  const float4* c4 = (const float4*)xc;
  float sab = 0.0f, sc = 0.0f;
#pragma unroll
  for (int k = 0; k < 4; ++k) {
    float4 va = a4[base4 + k * 256 + threadIdx.x];
    float4 vb = b4[base4 + k * 256 + threadIdx.x];
    float4 vc = c4[base4 + k * 256 + threadIdx.x];
    sab += (va.x + vb.x) + (va.y + vb.y) + (va.z + vb.z) + (va.w + vb.w);
    sc += vc.x + vc.y + vc.z + vc.w;
  }
#pragma unroll
  for (int m = 32; m; m >>= 1) {
    sab += __shfl_xor(sab, m, 64);
    sc += __shfl_xor(sc, m, 64);
  }
  __shared__ float pab[4], pc[4];
  if ((threadIdx.x & 63) == 0) {
    pab[threadIdx.x >> 6] = sab; pc[threadIdx.x >> 6] = sc;
  }
  __syncthreads();
  if (threadIdx.x == 0) {
    mean_ab[row] = (pab[0] + pab[1] + pab[2] + pab[3]) * (1.0f / 4096.0f);
    mean_c[row] = (pc[0] + pc[1] + pc[2] + pc[3]) * (1.0f / 4096.0f);
  }
}

// ============ global-pool attention branch (br = 1 or 3) ============
__global__ __launch_bounds__(256) void k_gatt(
    int br, const float* __restrict__ vinA, float scaleA,
    const float* __restrict__ vinB, float scaleB,
    const float* __restrict__ w1, const float* __restrict__ b1,
    const float* __restrict__ bn1g, const float* __restrict__ bn1b,
    const float* __restrict__ bn1m, const float* __restrict__ bn1v,
    const float* __restrict__ w2, const float* __restrict__ b2,
    const float* __restrict__ bn2g, const float* __restrict__ bn2b,
    const float* __restrict__ bn2m, const float* __restrict__ bn2v,
    float* __restrict__ gout)
{
  const int b = blockIdx.x, tid = threadIdx.x;
  __shared__ float xs[256];
  __shared__ float as[64];
  xs[tid] = vinA[(b << 8) + tid] * scaleA + vinB[(b << 8) + tid] * scaleB;
  __syncthreads();
  if (tid < 64) {
    const int gi = (br << 6) + tid;
    const float* wr = w1 + gi * 256;
    float acc = 0.0f;
#pragma unroll 8
    for (int c = 0; c < 256; ++c) acc = fmaf(wr[c], xs[c], acc);
    float s1 = bn1g[gi] / sqrtf(bn1v[gi] + EPS_);
    float h = s1 * (acc + b1[gi] - bn1m[gi]) + bn1b[gi];
    as[tid] = fmaxf(h, 0.0f);
  }
  __syncthreads();
  const int gc = (br << 8) + tid;
  const float* wr2 = w2 + gc * 64;
  float acc = 0.0f;
#pragma unroll 8
  for (int i = 0; i < 64; ++i) acc = fmaf(wr2[i], as[i], acc);
  float s2 = bn2g[gc] / sqrtf(bn2v[gc] + EPS_);
  gout[(b << 8) + tid] = s2 * (acc + b2[gc] - bn2m[gc]) + bn2b[gc];
}

// ============ K2: local branch 0 + first blend (MFMA f16, no LDS staging) ====
// 2048 blocks x 256 thr (4 waves); block = (b, 64-l tile); wave = 16-l cols.
// B fragments loaded DIRECTLY from global (coalesced: 4x64B segments/instr).
__global__ __launch_bounds__(256) void k_local1(
    const float* __restrict__ xa, const float* __restrict__ xb,
    const _Float16* __restrict__ W1A, const _Float16* __restrict__ W2A,
    const float* __restrict__ c1, const float* __restrict__ c2,
    const float* __restrict__ g1,
    float* __restrict__ xo1, _Float16* __restrict__ wei16,
    float* __restrict__ sumxo)
{
  const int tid = threadIdx.x;
  const int lane = tid & 63;
  const int ct = tid >> 6;
  const int b = blockIdx.x >> 6;
  const int l0 = (blockIdx.x & 63) << 6;
  __shared__ float cgs[256];
  __shared__ float c1s[64];
  __shared__ float sblk[256];

  cgs[tid] = c2[tid] + g1[(b << 8) + tid];
  if (tid < 64) c1s[tid] = c1[tid];
  sblk[tid] = 0.0f;
  __syncthreads();

  const int g4 = (lane >> 4) << 2;                 // 4*(lane>>4)
  const int col = l0 + (ct << 4) + (lane & 15);    // this lane's position
  const size_t gbase = ((size_t)b << 20) + (size_t)col;
  const float* __restrict__ xab = xa + gbase;      // + c*4096 per channel
  const float* __restrict__ xbb = xb + gbase;

  // ---- layer 1: h rows via MFMA; B-frag from global, sigma-consistent ----
  f32x4 acc1[4] = {{0,0,0,0},{0,0,0,0},{0,0,0,0},{0,0,0,0}};
  const f16x8* __restrict__ w1a = (const f16x8*)W1A;
#pragma unroll
  for (int kk = 0; kk < 8; ++kk) {
    union { f16x8 v; _Float16 e[8]; } bu;
#pragma unroll
    for (int e = 0; e < 8; ++e) {
      const int c = (kk << 5) + g4 + (e & 3) + ((e >> 2) << 4);
      const size_t o = (size_t)c << 12;
      bu.e[e] = (_Float16)(xab[o] + xbb[o]);
    }
    acc1[0] = MFMA16(w1a[(0 * 8 + kk) * 64 + lane], bu.v, acc1[0]);
    acc1[1] = MFMA16(w1a[(1 * 8 + kk) * 64 + lane], bu.v, acc1[1]);
    acc1[2] = MFMA16(w1a[(2 * 8 + kk) * 64 + lane], bu.v, acc1[2]);
    acc1[3] = MFMA16(w1a[(3 * 8 + kk) * 64 + lane], bu.v, acc1[3]);
  }

  // ---- bias+ReLU -> lane-local B2 fragments (uses only verified D layout) --
  f16x8 hb[2];
#pragma unroll
  for (int half = 0; half < 2; ++half) {
    union { f16x8 v; _Float16 e[8]; } hu;
#pragma unroll
    for (int q = 0; q < 2; ++q) {
      const int it = half * 2 + q;
      const int ib = it * 16 + g4;
#pragma unroll
      for (int r = 0; r < 4; ++r)
        hu.e[q * 4 + r] = (_Float16)fmaxf(acc1[it][r] + c1s[ib + r], 0.0f);
    }
    hb[half] = hu.v;
  }

  // ---- layer 2 + sigmoid + blend epilogue ----
  const f16x8* __restrict__ w2a = (const f16x8*)W2A;
#pragma unroll 2
  for (int rt = 0; rt < 16; ++rt) {
    f32x4 acc2 = {0, 0, 0, 0};
    acc2 = MFMA16(w2a[(rt * 2 + 0) * 64 + lane], hb[0], acc2);
    acc2 = MFMA16(w2a[(rt * 2 + 1) * 64 + lane], hb[1], acc2);
#pragma unroll
    for (int r = 0; r < 4; ++r) {
      const int c = (rt << 4) + g4 + r;
      const size_t o = (size_t)c << 12;
      const float t = acc2[r] + cgs[c];
      const float w = 1.0f / (1.0f + __expf(-t));
      const float av = xab[o], bv = xbb[o];
      const float xo = fmaf(av - bv, w, bv);     // a*w + b*(1-w)
      xo1[gbase + o] = xo;
      wei16[gbase + o] = (_Float16)w;
      float s = xo;
      s += __shfl_xor(s, 1, 64); s += __shfl_xor(s, 2, 64);
      s += __shfl_xor(s, 4, 64); s += __shfl_xor(s, 8, 64);
      if ((lane & 15) == 0) atomicAdd(&sblk[c], s);
    }
  }
  __syncthreads();
  atomicAdd(&sumxo[(b << 8) + tid], sblk[tid]);
}

// ============ K4: local branch 2 + final combine (MFMA f16) ============
// out = 0.5*xo1*(1+wei2) + 0.5*(1-wei1)*xc
__global__ __launch_bounds__(256) void k_local2(
    const float* __restrict__ xo1g, const float* __restrict__ xc,
    const _Float16* __restrict__ W1A, const _Float16* __restrict__ W2A,
    const float* __restrict__ c1, const float* __restrict__ c2,
    const float* __restrict__ g3, const _Float16* __restrict__ wei16,
    float* __restrict__ outp)
{
  const int tid = threadIdx.x;
  const int lane = tid & 63;
  const int ct = tid >> 6;
  const int b = blockIdx.x >> 6;
  const int l0 = (blockIdx.x & 63) << 6;
  __shared__ float cgs[256];
  __shared__ float c1s[64];

  cgs[tid] = c2[tid] + g3[(b << 8) + tid];
  if (tid < 64) c1s[tid] = c1[tid];
  __syncthreads();

  const int g4 = (lane >> 4) << 2;
  const int col = l0 + (ct << 4) + (lane & 15);
  const size_t gbase = ((size_t)b << 20) + (size_t)col;
  const float* __restrict__ xob = xo1g + gbase;
  const float* __restrict__ xcb = xc + gbase;

  f32x4 acc1[4] = {{0,0,0,0},{0,0,0,0},{0,0,0,0},{0,0,0,0}};
  const f16x8* __restrict__ w1a = (const f16x8*)W1A;
#pragma unroll
  for (int kk = 0; kk < 8; ++kk) {
    union { f16x8 v; _Float16 e[8]; } bu;
#pragma unroll
    for (int e = 0; e < 8; ++e) {
      const int c = (kk << 5) + g4 + (e & 3) + ((e >> 2) << 4);
      const size_t o = (size_t)c << 12;
      bu.e[e] = (_Float16)(xob[o] + xcb[o]);
    }
    acc1[0] = MFMA16(w1a[(0 * 8 + kk) * 64 + lane], bu.v, acc1[0]);
    acc1[1] = MFMA16(w1a[(1 * 8 + kk) * 64 + lane], bu.v, acc1[1]);
    acc1[2] = MFMA16(w1a[(2 * 8 + kk) * 64 + lane], bu.v, acc1[2]);
    acc1[3] = MFMA16(w1a[(3 * 8 + kk) * 64 + lane], bu.v, acc1[3]);
  }

  f16x8 hb[2];
#pragma unroll
  for (int half = 0; half < 2; ++half) {
    union { f16x8 v; _Float16 e[8]; } hu;
#pragma unroll
    for (int q = 0; q < 2; ++q) {
      const int it = half * 2 + q;
      const int ib = it * 16 + g4;
#pragma unroll
      for (int r = 0; r < 4; ++r)
        hu.e[q * 4 + r] = (_Float16)fmaxf(acc1[it][r] + c1s[ib + r], 0.0f);
    }
    hb[half] = hu.v;
  }

  const f16x8* __restrict__ w2a = (const f16x8*)W2A;
#pragma unroll 2
  for (int rt = 0; rt < 16; ++rt) {
    f32x4 acc2 = {0, 0, 0, 0};
    acc2 = MFMA16(w2a[(rt * 2 + 0) * 64 + lane], hb[0], acc2);
    acc2 = MFMA16(w2a[(rt * 2 + 1) * 64 + lane], hb[1], acc2);
#pragma unroll
    for (int r = 0; r < 4; ++r) {
      const int c = (rt << 4) + g4 + r;
      const size_t o = (size_t)c << 12;
      const float t = acc2[r] + cgs[c];
      const float w2v = 1.0f / (1.0f + __expf(-t));
      const float xov = xob[o];
      const float xcv = xcb[o];
      const float w1v = (float)wei16[gbase + o];
      outp[gbase + o] = fmaf(0.5f * xov, w2v,
                             fmaf(0.5f, xov, 0.5f * (1.0f - w1v) * xcv));
    }
  }
}

extern "C" void kernel_launch(void* const* d_in, const int* in_sizes, int n_in,
                              void* d_out, int out_size, void* d_ws, size_t ws_size,
                              hipStream_t stream) {
  const float* xa = (const float*)d_in[0];
  const float* xb = (const float*)d_in[1];
  const float* xc = (const float*)d_in[2];
  const float* w1 = (const float*)d_in[3];
  const float* b1 = (const float*)d_in[4];
  const float* bn1g = (const float*)d_in[5];
  const float* bn1b = (const float*)d_in[6];
  const float* bn1m = (const float*)d_in[7];
  const float* bn1v = (const float*)d_in[8];
  const float* w2 = (const float*)d_in[9];
  const float* b2 = (const float*)d_in[10];
  const float* bn2g = (const float*)d_in[11];
  const float* bn2b = (const float*)d_in[12];
  const float* bn2m = (const float*)d_in[13];
  const float* bn2v = (const float*)d_in[14];
  float* ws = (float*)d_ws;
  _Float16* ws16 = (_Float16*)d_ws;
  float* outp = (float*)d_out;

  _Float16* W1A0 = ws16;
  _Float16* W1A2 = ws16 + 16384;
  _Float16* W2A0 = ws16 + 32768;
  _Float16* W2A2 = ws16 + 49152;
  float* c1_0 = ws + OFF_C1_0;
  float* c1_2 = ws + OFF_C1_2;
  float* c2_0 = ws + OFF_C2_0;
  float* c2_2 = ws + OFF_C2_2;
  float* mean_ab = ws + OFF_MEANAB;
  float* mean_c = ws + OFF_MEANC;
  float* sumxo = ws + OFF_SUMXO;
  float* g1 = ws + OFF_G1;
  float* g3 = ws + OFF_G3;
  float* xo1 = ws + OFF_XO1;
  _Float16* wei16 = (_Float16*)(ws + OFF_WEI16);

  // 1) fold BN into fragment-ordered f16 weights; zero sumxo
  k_prep<<<291, 256, 0, stream>>>(w1, b1, bn1g, bn1b, bn1m, bn1v,
                                  w2, b2, bn2g, bn2b, bn2m, bn2v, ws);
  // 2) means over L of x_a+x_b and x_c
  k_mean3<<<8192, 256, 0, stream>>>(xa, xb, xc, mean_ab, mean_c);
  // 3) global-pool branch 1 (input = mean_ab)
  k_gatt<<<32, 256, 0, stream>>>(1, mean_ab, 1.0f, mean_ab, 0.0f,
                                 w1, b1, bn1g, bn1b, bn1m, bn1v,
                                 w2, b2, bn2g, bn2b, bn2m, bn2v, g1);
  // 4) local branch 0 + blend -> xo1, wei16, sumxo
  k_local1<<<2048, 256, 0, stream>>>(xa, xb, W1A0, W2A0, c1_0, c2_0, g1,
                                     xo1, wei16, sumxo);
  // 5) global-pool branch 3 (input = sumxo/4096 + mean_c)
  k_gatt<<<32, 256, 0, stream>>>(3, sumxo, 1.0f / 4096.0f, mean_c, 1.0f,
                                 w1, b1, bn1g, bn1b, bn1m, bn1v,
                                 w2, b2, bn2g, bn2b, bn2m, bn2v, g3);
  // 6) local branch 2 + final combine -> out
  k_local2<<<2048, 256, 0, stream>>>(xo1, xc, W1A2, W2A2, c1_2, c2_2, g3,
                                     wei16, outp);
}